// Round 4
// baseline (288.616 us; speedup 1.0000x reference)
//
#include <hip/hip_runtime.h>
#include <stdint.h>

#define B_  4
#define NQ_ 2048
#define NP_ 8192
#define D_  256
#define F_  40
#define K_  16

// ---------------- Kernel 1: hash codes -------------------------------------
// Block = 256 threads / 64 vectors. Two 128-dim LDS chunks (64x129 fp32,
// 33 KB -> 4 blocks/CU). Wave w computes features [10w,10w+10) for vector =
// lane. proj reads are wave-uniform, chunked x8 -> wide s_load. fmaf chain
// order d=0..255 sequential (bit-identical to passing rounds).
__global__ __launch_bounds__(256) void hash_kernel(
    const float* __restrict__ qp, const float* __restrict__ pp,
    const float* __restrict__ proj, uint64_t* __restrict__ qcodes,
    uint64_t* __restrict__ pcodes) {
  __shared__ float tile[64 * 129];  // 33024 B
  int t = threadIdx.x;
  int v0 = blockIdx.x * 64;
  bool isQ = v0 < B_ * NQ_;
  const float* src =
      isQ ? (qp + (size_t)v0 * D_) : (pp + (size_t)(v0 - B_ * NQ_) * D_);

  int lane = t & 63, w = t >> 6;
  int fbase = __builtin_amdgcn_readfirstlane(w * 10);
  const float* pj = proj + (size_t)fbase * 256;

  float acc[10];
#pragma unroll
  for (int f = 0; f < 10; ++f) acc[f] = 0.0f;

  int srow = t >> 7, scol = t & 127;  // staging: 2 rows per iter, coalesced
#pragma unroll
  for (int chunk = 0; chunk < 2; ++chunk) {
    int doff = chunk * 128;
    __syncthreads();
#pragma unroll 8
    for (int i = 0; i < 32; ++i) {
      int row = i * 2 + srow;
      tile[row * 129 + scol] = src[row * 256 + doff + scol];
    }
    __syncthreads();
#pragma unroll
    for (int dc = 0; dc < 128; dc += 8) {
      float x8[8];
#pragma unroll
      for (int u = 0; u < 8; ++u) x8[u] = tile[lane * 129 + dc + u];
      const float* prow = pj + doff + dc;  // uniform base
#pragma unroll
      for (int f = 0; f < 10; ++f) {
#pragma unroll
        for (int u = 0; u < 8; ++u)
          acc[f] = fmaf(x8[u], prow[f * 256 + u], acc[f]);
      }
    }
  }
  unsigned bits = 0;
#pragma unroll
  for (int f = 0; f < 10; ++f)
    if (acc[f] > 0.0f) bits |= 1u << f;

  __syncthreads();
  unsigned short* cb = (unsigned short*)tile;
  cb[lane * 4 + w] = (unsigned short)bits;
  __syncthreads();
  if (w == 0) {
    uint64_t code = (uint64_t)cb[lane * 4 + 0] |
                    ((uint64_t)cb[lane * 4 + 1] << 10) |
                    ((uint64_t)cb[lane * 4 + 2] << 20) |
                    ((uint64_t)cb[lane * 4 + 3] << 30);
    int gv = v0 + lane;
    if (isQ) qcodes[gv] = code;
    else pcodes[gv - B_ * NQ_] = code;
  }
}

// ---------------- Kernel 2: exact top-16 by (dist, index) -------------------
// 1024-thread block = 16 query-waves, one 64KB code tile. Single LDS sweep
// computes distances (<=40) and packs 4-per-u32 into 32 VGPRs; fine
// histogram + ordered collection run from registers. NO min-waves launch
// bound: natural VGPR allocation, no spill/scratch (R3 crash suspect).
__global__ __launch_bounds__(1024) void select_kernel(
    const uint64_t* __restrict__ qcodes, const uint64_t* __restrict__ pcodes,
    float* __restrict__ outIdx, float* __restrict__ outDist) {
  __shared__ uint64_t ldsP[NP_];  // 64 KB
  __shared__ unsigned keybuf[16][K_];

  int tid = threadIdx.x;
  int bb = blockIdx.x >> 7;  // 128 blocks per batch
  const uint64_t* pb = pcodes + (size_t)bb * NP_;
  for (int i = tid; i < NP_; i += 1024) ldsP[i] = pb[i];
  __syncthreads();

  int w = tid >> 6, lane = tid & 63;
  int qg = blockIdx.x * 16 + w;
  uint64_t qc = qcodes[qg];
  const uint64_t M = 0x00FF00FF00FF00FFull;

  // ---- Pass A: one LDS sweep -> coarse byte histogram + packed distances --
  unsigned dpack[32];  // 4 x 8-bit distances per u32, point p = j*64+lane
  uint64_t c8 = 0;
#pragma unroll
  for (int jw = 0; jw < 32; ++jw) {
    unsigned b0, b1, b2, b3;
#pragma unroll
    for (int s = 0; s < 4; ++s) {
      uint64_t pc = ldsP[(jw * 4 + s) * 64 + lane];
      unsigned d = (unsigned)__popcll(qc ^ pc);
      c8 += 1ull << (d & 56);  // bucket d>>3 (d<=40 -> shift<=40)
      if (s == 0) b0 = d; else if (s == 1) b1 = d;
      else if (s == 2) b2 = d; else b3 = d;
    }
    dpack[jw] = b0 | (b1 << 8) | (b2 << 16) | (b3 << 24);
  }
  uint64_t e = c8 & M, o = (c8 >> 8) & M;
#pragma unroll
  for (int s = 1; s < 64; s <<= 1) { e += __shfl_xor(e, s); o += __shfl_xor(o, s); }
  int Bb = 0; unsigned nbefore = 0, cum = 0; bool found = false;
#pragma unroll
  for (int k2 = 0; k2 < 6; ++k2) {
    unsigned c = (unsigned)(((k2 & 1) ? o : e) >> ((k2 >> 1) * 16)) & 0xFFFFu;
    if (!found && cum + c >= K_) { Bb = k2; nbefore = cum; found = true; }
    cum += c;
  }

  // ---- Pass B: fine histogram of bucket Bb from registers ----
  unsigned base = (unsigned)(Bb * 8);
  uint64_t cf = 0;
#pragma unroll
  for (int jw = 0; jw < 32; ++jw) {
    unsigned word = dpack[jw];
#pragma unroll
    for (int s = 0; s < 4; ++s) {
      unsigned rel = ((word >> (s * 8)) & 0xFFu) - base;
      if (rel < 8u) cf += 1ull << (rel << 3);
    }
  }
  e = cf & M; o = (cf >> 8) & M;
#pragma unroll
  for (int s = 1; s < 64; s <<= 1) { e += __shfl_xor(e, s); o += __shfl_xor(o, s); }
  int thr = 0; unsigned n_lt = 0; cum = nbefore; found = false;
#pragma unroll
  for (int r = 0; r < 8; ++r) {
    unsigned c = (unsigned)(((r & 1) ? o : e) >> ((r >> 1) * 16)) & 0xFFFFu;
    if (!found && cum + c >= K_) { thr = (int)(base + r); n_lt = cum; found = true; }
    cum += c;
  }
  unsigned r_need = K_ - n_lt;  // dist==thr entries to take (lowest index)

  // ---- Pass C: ordered collection from registers ----
  unsigned cl = 0, ce = 0;
  uint64_t lmask = (1ull << lane) - 1;
#pragma unroll
  for (int jw = 0; jw < 32; ++jw) {
    unsigned word = dpack[jw];
#pragma unroll
    for (int s = 0; s < 4; ++s) {
      int d = (int)((word >> (s * 8)) & 0xFFu);
      uint64_t mlt = __ballot(d < thr);
      uint64_t meq = __ballot(d == thr);
      if (mlt | meq) {
        int p = (jw * 4 + s) * 64 + lane;
        if (d < thr)
          keybuf[w][cl + (unsigned)__popcll(mlt & lmask)] =
              ((unsigned)d << 13) | (unsigned)p;
        if (d == thr) {
          unsigned pos = ce + (unsigned)__popcll(meq & lmask);
          if (pos < r_need)
            keybuf[w][n_lt + pos] = ((unsigned)d << 13) | (unsigned)p;
        }
        cl += (unsigned)__popcll(mlt);
        ce += (unsigned)__popcll(meq);
      }
    }
  }
  __syncthreads();

  // ---- rank-sort the 16 keys (distinct: idx embedded) and emit ----
  if (lane < K_) {
    unsigned my = keybuf[w][lane];
    int rank = 0;
#pragma unroll
    for (int jj = 0; jj < K_; ++jj) rank += (keybuf[w][jj] < my) ? 1 : 0;
    int off = qg * K_ + rank;
    outIdx[off]  = (float)(my & 8191u);  // index
    outDist[off] = (float)(my >> 13);    // distance
  }
}

extern "C" void kernel_launch(void* const* d_in, const int* in_sizes, int n_in,
                              void* d_out, int out_size, void* d_ws, size_t ws_size,
                              hipStream_t stream) {
  const float* qp   = (const float*)d_in[0];
  const float* pp   = (const float*)d_in[1];
  const float* proj = (const float*)d_in[2];
  // d_in[3] is k (always 16) — hardcoded.

  uint64_t* pcodes = (uint64_t*)d_ws;            // B*NP u64
  uint64_t* qcodes = pcodes + (size_t)B_ * NP_;  // B*NQ u64

  float* outIdx  = (float*)d_out;                   // B*NQ*K indices (as float)
  float* outDist = outIdx + (size_t)B_ * NQ_ * K_;  // B*NQ*K distances

  int total_vecs = B_ * (NQ_ + NP_);  // 40960
  hash_kernel<<<total_vecs / 64, 256, 0, stream>>>(qp, pp, proj, qcodes, pcodes);
  select_kernel<<<B_ * NQ_ / 16, 1024, 0, stream>>>(qcodes, pcodes, outIdx, outDist);
}

// Round 5
// 283.899 us; speedup vs baseline: 1.0166x; 1.0166x over previous
//
#include <hip/hip_runtime.h>
#include <stdint.h>

#define B_  4
#define NQ_ 2048
#define NP_ 8192
#define D_  256
#define F_  40
#define K_  16

// ---------------- Kernel 1: hash codes -------------------------------------
// Block = 512 threads / 64 vectors, 8 waves x 5 features. LDS x-tile staged
// in two 128-dim chunks (64x130 fp32, 33.3 KB). proj reads wave-uniform ->
// scalar loads (5 rows in flight). fmaf chain d=0..255 sequential per
// (vector,feature) — bit-identical to all passing rounds.
__global__ __launch_bounds__(512) void hash_kernel(
    const float* __restrict__ qp, const float* __restrict__ pp,
    const float* __restrict__ proj, uint64_t* __restrict__ qcodes,
    uint64_t* __restrict__ pcodes) {
  __shared__ float tile[64 * 130];  // 33280 B
  int t = threadIdx.x;
  int v0 = blockIdx.x * 64;
  bool isQ = v0 < B_ * NQ_;
  const float* src =
      isQ ? (qp + (size_t)v0 * D_) : (pp + (size_t)(v0 - B_ * NQ_) * D_);

  int lane = t & 63, w = t >> 6;  // w in [0,8)
  int fbase = __builtin_amdgcn_readfirstlane(w * 5);
  const float* pj = proj + (size_t)fbase * 256;

  float acc[5];
#pragma unroll
  for (int f = 0; f < 5; ++f) acc[f] = 0.0f;

  int srow = t >> 7, scol = t & 127;  // staging: 4 rows per iter, coalesced
#pragma unroll
  for (int chunk = 0; chunk < 2; ++chunk) {
    int doff = chunk * 128;
    __syncthreads();
#pragma unroll
    for (int i = 0; i < 16; ++i) {
      int row = i * 4 + srow;
      tile[row * 130 + scol] = src[row * 256 + doff + scol];
    }
    __syncthreads();
#pragma unroll
    for (int dc = 0; dc < 128; dc += 8) {
      float x8[8];
#pragma unroll
      for (int u = 0; u < 8; ++u) x8[u] = tile[lane * 130 + dc + u];
      const float* prow = pj + doff + dc;  // uniform base -> s_load
#pragma unroll
      for (int f = 0; f < 5; ++f) {
#pragma unroll
        for (int u = 0; u < 8; ++u)
          acc[f] = fmaf(x8[u], prow[f * 256 + u], acc[f]);
      }
    }
  }
  unsigned bits = 0;
#pragma unroll
  for (int f = 0; f < 5; ++f)
    if (acc[f] > 0.0f) bits |= 1u << f;

  // Combine 8 waves' 5-bit chunks per vector (reuse tile as u16 scratch).
  __syncthreads();
  unsigned short* cb = (unsigned short*)tile;
  cb[lane * 8 + w] = (unsigned short)bits;
  __syncthreads();
  if (w == 0) {
    uint64_t code = 0;
#pragma unroll
    for (int i = 0; i < 8; ++i)
      code |= (uint64_t)cb[lane * 8 + i] << (5 * i);
    int gv = v0 + lane;
    if (isQ) qcodes[gv] = code;
    else pcodes[gv - B_ * NQ_] = code;
  }
}

// ---------------- Kernel 2: exact top-16 by (dist, index) -------------------
// 512-thread block = 8 query-waves, one 64KB code tile (2 blocks/CU).
// __launch_bounds__(512,4) -> VGPR cap 128: dpack[32] stays in registers
// (R4's 64-VGPR cap spilled it -> 637MB scratch traffic -> 175us).
// Single LDS sweep computes all distances; fine histogram + ordered
// collection run from registers.
__global__ __launch_bounds__(512, 4) void select_kernel(
    const uint64_t* __restrict__ qcodes, const uint64_t* __restrict__ pcodes,
    float* __restrict__ outIdx, float* __restrict__ outDist) {
  __shared__ uint64_t ldsP[NP_];  // 64 KB
  __shared__ unsigned keybuf[8][K_];

  int tid = threadIdx.x;
  int bb = blockIdx.x >> 8;  // 256 blocks per batch
  const uint64_t* pb = pcodes + (size_t)bb * NP_;
  for (int i = tid; i < NP_; i += 512) ldsP[i] = pb[i];
  __syncthreads();

  int w = tid >> 6, lane = tid & 63;
  int qg = blockIdx.x * 8 + w;
  uint64_t qc = qcodes[qg];
  const uint64_t M = 0x00FF00FF00FF00FFull;

  // ---- Pass A: one LDS sweep -> coarse byte histogram + packed distances --
  unsigned dpack[32];  // 4 x 8-bit distances per u32, point p = j*64+lane
  uint64_t c8 = 0;
#pragma unroll
  for (int jw = 0; jw < 32; ++jw) {
    unsigned b0, b1, b2, b3;
#pragma unroll
    for (int s = 0; s < 4; ++s) {
      uint64_t pc = ldsP[(jw * 4 + s) * 64 + lane];
      unsigned d = (unsigned)__popcll(qc ^ pc);
      c8 += 1ull << (d & 56);  // bucket d>>3 (d<=40)
      if (s == 0) b0 = d; else if (s == 1) b1 = d;
      else if (s == 2) b2 = d; else b3 = d;
    }
    dpack[jw] = b0 | (b1 << 8) | (b2 << 16) | (b3 << 24);
  }
  uint64_t e = c8 & M, o = (c8 >> 8) & M;
#pragma unroll
  for (int s = 1; s < 64; s <<= 1) { e += __shfl_xor(e, s); o += __shfl_xor(o, s); }
  int Bb = 0; unsigned nbefore = 0, cum = 0; bool found = false;
#pragma unroll
  for (int k2 = 0; k2 < 6; ++k2) {
    unsigned c = (unsigned)(((k2 & 1) ? o : e) >> ((k2 >> 1) * 16)) & 0xFFFFu;
    if (!found && cum + c >= K_) { Bb = k2; nbefore = cum; found = true; }
    cum += c;
  }

  // ---- Pass B: fine histogram of bucket Bb from registers ----
  unsigned base = (unsigned)(Bb * 8);
  uint64_t cf = 0;
#pragma unroll
  for (int jw = 0; jw < 32; ++jw) {
    unsigned word = dpack[jw];
#pragma unroll
    for (int s = 0; s < 4; ++s) {
      unsigned rel = ((word >> (s * 8)) & 0xFFu) - base;
      if (rel < 8u) cf += 1ull << (rel << 3);
    }
  }
  e = cf & M; o = (cf >> 8) & M;
#pragma unroll
  for (int s = 1; s < 64; s <<= 1) { e += __shfl_xor(e, s); o += __shfl_xor(o, s); }
  int thr = 0; unsigned n_lt = 0; cum = nbefore; found = false;
#pragma unroll
  for (int r = 0; r < 8; ++r) {
    unsigned c = (unsigned)(((r & 1) ? o : e) >> ((r >> 1) * 16)) & 0xFFFFu;
    if (!found && cum + c >= K_) { thr = (int)(base + r); n_lt = cum; found = true; }
    cum += c;
  }
  unsigned r_need = K_ - n_lt;  // dist==thr entries to take (lowest index)

  // ---- Pass C: ordered collection from registers ----
  unsigned cl = 0, ce = 0;
  uint64_t lmask = (1ull << lane) - 1;
#pragma unroll
  for (int jw = 0; jw < 32; ++jw) {
    unsigned word = dpack[jw];
#pragma unroll
    for (int s = 0; s < 4; ++s) {
      int d = (int)((word >> (s * 8)) & 0xFFu);
      uint64_t mlt = __ballot(d < thr);
      uint64_t meq = __ballot(d == thr);
      if (mlt | meq) {
        int p = (jw * 4 + s) * 64 + lane;
        if (d < thr)
          keybuf[w][cl + (unsigned)__popcll(mlt & lmask)] =
              ((unsigned)d << 13) | (unsigned)p;
        if (d == thr) {
          unsigned pos = ce + (unsigned)__popcll(meq & lmask);
          if (pos < r_need)
            keybuf[w][n_lt + pos] = ((unsigned)d << 13) | (unsigned)p;
        }
        cl += (unsigned)__popcll(mlt);
        ce += (unsigned)__popcll(meq);
      }
    }
  }
  __syncthreads();

  // ---- rank-sort the 16 keys (distinct: idx embedded) and emit ----
  if (lane < K_) {
    unsigned my = keybuf[w][lane];
    int rank = 0;
#pragma unroll
    for (int jj = 0; jj < K_; ++jj) rank += (keybuf[w][jj] < my) ? 1 : 0;
    int off = qg * K_ + rank;
    outIdx[off]  = (float)(my & 8191u);  // index
    outDist[off] = (float)(my >> 13);    // distance
  }
}

extern "C" void kernel_launch(void* const* d_in, const int* in_sizes, int n_in,
                              void* d_out, int out_size, void* d_ws, size_t ws_size,
                              hipStream_t stream) {
  const float* qp   = (const float*)d_in[0];
  const float* pp   = (const float*)d_in[1];
  const float* proj = (const float*)d_in[2];
  // d_in[3] is k (always 16) — hardcoded.

  uint64_t* pcodes = (uint64_t*)d_ws;            // B*NP u64
  uint64_t* qcodes = pcodes + (size_t)B_ * NP_;  // B*NQ u64

  float* outIdx  = (float*)d_out;                   // B*NQ*K indices (as float)
  float* outDist = outIdx + (size_t)B_ * NQ_ * K_;  // B*NQ*K distances

  int total_vecs = B_ * (NQ_ + NP_);  // 40960
  hash_kernel<<<total_vecs / 64, 512, 0, stream>>>(qp, pp, proj, qcodes, pcodes);
  select_kernel<<<B_ * NQ_ / 8, 512, 0, stream>>>(qcodes, pcodes, outIdx, outDist);
}

// Round 6
// 197.162 us; speedup vs baseline: 1.4639x; 1.4399x over previous
//
#include <hip/hip_runtime.h>
#include <stdint.h>

#define B_  4
#define NQ_ 2048
#define NP_ 8192
#define D_  256
#define F_  40
#define K_  16

// ---------------- Kernel 1: hash codes -------------------------------------
// Block = 512 threads / 64 vectors, 8 waves x 5 features. LDS x-tile staged
// in two 128-dim chunks (64x130 fp32, 33.3 KB). proj reads wave-uniform ->
// scalar loads. fmaf chain d=0..255 sequential per (vector,feature) —
// bit-identical to all passing rounds.
__global__ __launch_bounds__(512) void hash_kernel(
    const float* __restrict__ qp, const float* __restrict__ pp,
    const float* __restrict__ proj, uint64_t* __restrict__ qcodes,
    uint64_t* __restrict__ pcodes) {
  __shared__ float tile[64 * 130];  // 33280 B
  int t = threadIdx.x;
  int v0 = blockIdx.x * 64;
  bool isQ = v0 < B_ * NQ_;
  const float* src =
      isQ ? (qp + (size_t)v0 * D_) : (pp + (size_t)(v0 - B_ * NQ_) * D_);

  int lane = t & 63, w = t >> 6;  // w in [0,8)
  int fbase = __builtin_amdgcn_readfirstlane(w * 5);
  const float* pj = proj + (size_t)fbase * 256;

  float acc[5];
#pragma unroll
  for (int f = 0; f < 5; ++f) acc[f] = 0.0f;

  int srow = t >> 7, scol = t & 127;  // staging: 4 rows per iter, coalesced
#pragma unroll
  for (int chunk = 0; chunk < 2; ++chunk) {
    int doff = chunk * 128;
    __syncthreads();
#pragma unroll
    for (int i = 0; i < 16; ++i) {
      int row = i * 4 + srow;
      tile[row * 130 + scol] = src[row * 256 + doff + scol];
    }
    __syncthreads();
#pragma unroll
    for (int dc = 0; dc < 128; dc += 8) {
      float x8[8];
#pragma unroll
      for (int u = 0; u < 8; ++u) x8[u] = tile[lane * 130 + dc + u];
      const float* prow = pj + doff + dc;  // uniform base -> s_load
#pragma unroll
      for (int f = 0; f < 5; ++f) {
#pragma unroll
        for (int u = 0; u < 8; ++u)
          acc[f] = fmaf(x8[u], prow[f * 256 + u], acc[f]);
      }
    }
  }
  unsigned bits = 0;
#pragma unroll
  for (int f = 0; f < 5; ++f)
    if (acc[f] > 0.0f) bits |= 1u << f;

  // Combine 8 waves' 5-bit chunks per vector (reuse tile as u16 scratch).
  __syncthreads();
  unsigned short* cb = (unsigned short*)tile;
  cb[lane * 8 + w] = (unsigned short)bits;
  __syncthreads();
  if (w == 0) {
    uint64_t code = 0;
#pragma unroll
    for (int i = 0; i < 8; ++i)
      code |= (uint64_t)cb[lane * 8 + i] << (5 * i);
    int gv = v0 + lane;
    if (isQ) qcodes[gv] = code;
    else pcodes[gv - B_ * NQ_] = code;
  }
}

// ---------------- Kernel 2: exact top-16 by (dist, index) -------------------
// 512-thread block = 8 query-waves, one 64KB code tile (2 blocks/CU via LDS).
// amdgpu_waves_per_eu(2) -> VGPR budget 256: dpack[32] stays in registers.
// (R4/R5: default/launch_bounds budgets resolved to 64 VGPR -> dpack spilled
// -> ~600MB scratch traffic -> 175-241us. LLVM attribute is unambiguous.)
// Single LDS sweep computes all distances; fine histogram + ordered
// collection run from registers.
__global__ __launch_bounds__(512)
__attribute__((amdgpu_waves_per_eu(2))) void select_kernel(
    const uint64_t* __restrict__ qcodes, const uint64_t* __restrict__ pcodes,
    float* __restrict__ outIdx, float* __restrict__ outDist) {
  __shared__ uint64_t ldsP[NP_];  // 64 KB
  __shared__ unsigned keybuf[8][K_];

  int tid = threadIdx.x;
  int bb = blockIdx.x >> 8;  // 256 blocks per batch
  const uint64_t* pb = pcodes + (size_t)bb * NP_;
  for (int i = tid; i < NP_; i += 512) ldsP[i] = pb[i];
  __syncthreads();

  int w = tid >> 6, lane = tid & 63;
  int qg = blockIdx.x * 8 + w;
  uint64_t qc = qcodes[qg];
  const uint64_t M = 0x00FF00FF00FF00FFull;

  // ---- Pass A: one LDS sweep -> coarse byte histogram + packed distances --
  unsigned dpack[32];  // 4 x 8-bit distances per u32, point p = j*64+lane
  uint64_t c8 = 0;
#pragma unroll
  for (int jw = 0; jw < 32; ++jw) {
    unsigned b0, b1, b2, b3;
#pragma unroll
    for (int s = 0; s < 4; ++s) {
      uint64_t pc = ldsP[(jw * 4 + s) * 64 + lane];
      unsigned d = (unsigned)__popcll(qc ^ pc);
      c8 += 1ull << (d & 56);  // bucket d>>3 (d<=40)
      if (s == 0) b0 = d; else if (s == 1) b1 = d;
      else if (s == 2) b2 = d; else b3 = d;
    }
    dpack[jw] = b0 | (b1 << 8) | (b2 << 16) | (b3 << 24);
  }
  uint64_t e = c8 & M, o = (c8 >> 8) & M;
#pragma unroll
  for (int s = 1; s < 64; s <<= 1) { e += __shfl_xor(e, s); o += __shfl_xor(o, s); }
  int Bb = 0; unsigned nbefore = 0, cum = 0; bool found = false;
#pragma unroll
  for (int k2 = 0; k2 < 6; ++k2) {
    unsigned c = (unsigned)(((k2 & 1) ? o : e) >> ((k2 >> 1) * 16)) & 0xFFFFu;
    if (!found && cum + c >= K_) { Bb = k2; nbefore = cum; found = true; }
    cum += c;
  }

  // ---- Pass B: fine histogram of bucket Bb from registers ----
  unsigned base = (unsigned)(Bb * 8);
  uint64_t cf = 0;
#pragma unroll
  for (int jw = 0; jw < 32; ++jw) {
    unsigned word = dpack[jw];
#pragma unroll
    for (int s = 0; s < 4; ++s) {
      unsigned rel = ((word >> (s * 8)) & 0xFFu) - base;
      if (rel < 8u) cf += 1ull << (rel << 3);
    }
  }
  e = cf & M; o = (cf >> 8) & M;
#pragma unroll
  for (int s = 1; s < 64; s <<= 1) { e += __shfl_xor(e, s); o += __shfl_xor(o, s); }
  int thr = 0; unsigned n_lt = 0; cum = nbefore; found = false;
#pragma unroll
  for (int r = 0; r < 8; ++r) {
    unsigned c = (unsigned)(((r & 1) ? o : e) >> ((r >> 1) * 16)) & 0xFFFFu;
    if (!found && cum + c >= K_) { thr = (int)(base + r); n_lt = cum; found = true; }
    cum += c;
  }
  unsigned r_need = K_ - n_lt;  // dist==thr entries to take (lowest index)

  // ---- Pass C: ordered collection from registers ----
  unsigned cl = 0, ce = 0;
  uint64_t lmask = (1ull << lane) - 1;
#pragma unroll
  for (int jw = 0; jw < 32; ++jw) {
    unsigned word = dpack[jw];
#pragma unroll
    for (int s = 0; s < 4; ++s) {
      int d = (int)((word >> (s * 8)) & 0xFFu);
      uint64_t mlt = __ballot(d < thr);
      uint64_t meq = __ballot(d == thr);
      if (mlt | meq) {
        int p = (jw * 4 + s) * 64 + lane;
        if (d < thr)
          keybuf[w][cl + (unsigned)__popcll(mlt & lmask)] =
              ((unsigned)d << 13) | (unsigned)p;
        if (d == thr) {
          unsigned pos = ce + (unsigned)__popcll(meq & lmask);
          if (pos < r_need)
            keybuf[w][n_lt + pos] = ((unsigned)d << 13) | (unsigned)p;
        }
        cl += (unsigned)__popcll(mlt);
        ce += (unsigned)__popcll(meq);
      }
    }
  }
  __syncthreads();

  // ---- rank-sort the 16 keys (distinct: idx embedded) and emit ----
  if (lane < K_) {
    unsigned my = keybuf[w][lane];
    int rank = 0;
#pragma unroll
    for (int jj = 0; jj < K_; ++jj) rank += (keybuf[w][jj] < my) ? 1 : 0;
    int off = qg * K_ + rank;
    outIdx[off]  = (float)(my & 8191u);  // index
    outDist[off] = (float)(my >> 13);    // distance
  }
}

extern "C" void kernel_launch(void* const* d_in, const int* in_sizes, int n_in,
                              void* d_out, int out_size, void* d_ws, size_t ws_size,
                              hipStream_t stream) {
  const float* qp   = (const float*)d_in[0];
  const float* pp   = (const float*)d_in[1];
  const float* proj = (const float*)d_in[2];
  // d_in[3] is k (always 16) — hardcoded.

  uint64_t* pcodes = (uint64_t*)d_ws;            // B*NP u64
  uint64_t* qcodes = pcodes + (size_t)B_ * NP_;  // B*NQ u64

  float* outIdx  = (float*)d_out;                   // B*NQ*K indices (as float)
  float* outDist = outIdx + (size_t)B_ * NQ_ * K_;  // B*NQ*K distances

  int total_vecs = B_ * (NQ_ + NP_);  // 40960
  hash_kernel<<<total_vecs / 64, 512, 0, stream>>>(qp, pp, proj, qcodes, pcodes);
  select_kernel<<<B_ * NQ_ / 8, 512, 0, stream>>>(qcodes, pcodes, outIdx, outDist);
}

// Round 7
// 173.254 us; speedup vs baseline: 1.6659x; 1.1380x over previous
//
#include <hip/hip_runtime.h>
#include <stdint.h>

#define B_  4
#define NQ_ 2048
#define NP_ 8192
#define D_  256
#define F_  40
#define K_  16

// ---------------- Kernel 1: hash codes -------------------------------------
// Block = 512 threads / 64 vectors, 8 waves x 5 features. ONE 64x256 LDS tile
// (stride 258: 8B-aligned ds_read_b64, bank stride 2 -> 2-way = free; 66 KB ->
// 2 blocks/CU). Single barrier between staging and compute; 32 unrolled
// dim-chunks give the scheduler room to hoist proj s_loads and x ds_reads.
// fmaf chain d=0..255 sequential per (vector,feature) — bit-identical to all
// passing rounds.
__global__ __launch_bounds__(512) void hash_kernel(
    const float* __restrict__ qp, const float* __restrict__ pp,
    const float* __restrict__ proj, uint64_t* __restrict__ qcodes,
    uint64_t* __restrict__ pcodes) {
  __shared__ float tile[64 * 258];  // 66048 B
  int t = threadIdx.x;
  int v0 = blockIdx.x * 64;
  bool isQ = v0 < B_ * NQ_;
  const float* src =
      isQ ? (qp + (size_t)v0 * D_) : (pp + (size_t)(v0 - B_ * NQ_) * D_);
  const float2* src2 = (const float2*)src;

  // Stage 64x256 floats as 8192 float2 (16 per thread, coalesced).
#pragma unroll
  for (int i = 0; i < 16; ++i) {
    int fidx = i * 512 + t;
    int row = fidx >> 7;          // 128 float2 per row
    int c2 = (fidx & 127) * 2;
    float2 v = src2[fidx];
    *(float2*)&tile[row * 258 + c2] = v;
  }
  __syncthreads();

  int lane = t & 63, w = t >> 6;  // w in [0,8)
  int fbase = __builtin_amdgcn_readfirstlane(w * 5);
  const float* pj = proj + (size_t)fbase * 256;

  float acc[5];
#pragma unroll
  for (int f = 0; f < 5; ++f) acc[f] = 0.0f;

#pragma unroll
  for (int dc = 0; dc < 256; dc += 8) {
    float x8[8];
#pragma unroll
    for (int u = 0; u < 4; ++u) {
      float2 xv = *(const float2*)&tile[lane * 258 + dc + 2 * u];
      x8[2 * u] = xv.x;
      x8[2 * u + 1] = xv.y;
    }
#pragma unroll
    for (int f = 0; f < 5; ++f) {
#pragma unroll
      for (int u = 0; u < 8; ++u)
        acc[f] = fmaf(x8[u], pj[f * 256 + dc + u], acc[f]);
    }
  }
  unsigned bits = 0;
#pragma unroll
  for (int f = 0; f < 5; ++f)
    if (acc[f] > 0.0f) bits |= 1u << f;

  // Combine 8 waves' 5-bit chunks per vector (reuse tile as u16 scratch).
  __syncthreads();
  unsigned short* cb = (unsigned short*)tile;
  cb[lane * 8 + w] = (unsigned short)bits;
  __syncthreads();
  if (w == 0) {
    uint64_t code = 0;
#pragma unroll
    for (int i = 0; i < 8; ++i)
      code |= (uint64_t)cb[lane * 8 + i] << (5 * i);
    int gv = v0 + lane;
    if (isQ) qcodes[gv] = code;
    else pcodes[gv - B_ * NQ_] = code;
  }
}

// ---------------- Kernel 2: exact top-16 by (dist, index) -------------------
// R2 structure (its 63us/VGPR=20/occ 64% beat R6's register-cached 96us):
// 1024-thread block = 16 query-waves, one 64KB code tile, 2 blocks/CU = full
// occupancy. Low VGPR is the winning resource trade on CDNA4 — re-reading LDS
// is cheaper than halving wave residency. 3 passes: coarse byte-histogram
// (pair-merged increments), fine histogram, guarded ordered collection.
__global__ __launch_bounds__(1024) void select_kernel(
    const uint64_t* __restrict__ qcodes, const uint64_t* __restrict__ pcodes,
    float* __restrict__ outIdx, float* __restrict__ outDist) {
  __shared__ uint64_t ldsP[NP_];  // 64 KB
  __shared__ unsigned keybuf[16][K_];

  int tid = threadIdx.x;
  int bb = blockIdx.x >> 7;  // 128 blocks per batch
  const uint64_t* pb = pcodes + (size_t)bb * NP_;
  for (int i = tid; i < NP_; i += 1024) ldsP[i] = pb[i];
  __syncthreads();

  int w = tid >> 6, lane = tid & 63;
  int qg = blockIdx.x * 16 + w;
  uint64_t qc = qcodes[qg];
  const uint64_t M = 0x00FF00FF00FF00FFull;
  const ulonglong2* ldsP2 = (const ulonglong2*)ldsP;

  // ---- Pass 1: coarse histogram of dist>>3 (6 byte-buckets), point pairs --
  uint64_t c8 = 0;
#pragma unroll 4
  for (int j = 0; j < 64; ++j) {
    ulonglong2 pc = ldsP2[j * 64 + lane];
    int d0 = __popcll(qc ^ pc.x);
    int d1 = __popcll(qc ^ pc.y);
    c8 += (1ull << (d0 & 56)) + (1ull << (d1 & 56));  // (d>>3)*8 == d&56
  }
  uint64_t e = c8 & M, o = (c8 >> 8) & M;
#pragma unroll
  for (int s = 1; s < 64; s <<= 1) { e += __shfl_xor(e, s); o += __shfl_xor(o, s); }
  int Bb = 0; unsigned nbefore = 0, cum = 0; bool found = false;
#pragma unroll
  for (int k2 = 0; k2 < 6; ++k2) {
    unsigned c = (unsigned)(((k2 & 1) ? o : e) >> ((k2 >> 1) * 16)) & 0xFFFFu;
    if (!found && cum + c >= K_) { Bb = k2; nbefore = cum; found = true; }
    cum += c;
  }

  // ---- Pass 2: fine histogram of the 8 dists inside bucket Bb ----
  unsigned base = (unsigned)(Bb * 8);
  uint64_t cf = 0;
#pragma unroll 4
  for (int j = 0; j < 64; ++j) {
    ulonglong2 pc = ldsP2[j * 64 + lane];
    unsigned r0 = (unsigned)__popcll(qc ^ pc.x) - base;
    unsigned r1 = (unsigned)__popcll(qc ^ pc.y) - base;
    if (r0 < 8u) cf += 1ull << (r0 << 3);
    if (r1 < 8u) cf += 1ull << (r1 << 3);
  }
  e = cf & M; o = (cf >> 8) & M;
#pragma unroll
  for (int s = 1; s < 64; s <<= 1) { e += __shfl_xor(e, s); o += __shfl_xor(o, s); }
  int thr = 0; unsigned n_lt = 0; cum = nbefore; found = false;
#pragma unroll
  for (int r = 0; r < 8; ++r) {
    unsigned c = (unsigned)(((r & 1) ? o : e) >> ((r >> 1) * 16)) & 0xFFFFu;
    if (!found && cum + c >= K_) { thr = (int)(base + r); n_lt = cum; found = true; }
    cum += c;
  }
  unsigned r_need = K_ - n_lt;  // dist==thr entries to take (lowest index)

  // ---- Pass 3: collect keys in index order; skip empty iterations ----
  unsigned cl = 0, ce = 0;
  uint64_t lmask = (1ull << lane) - 1;
  for (int j = 0; j < 128; ++j) {
    int p = j * 64 + lane;
    int d = __popcll(qc ^ ldsP[p]);
    if (__any(d <= thr)) {
      bool blt = (d < thr), beq = (d == thr);
      uint64_t mlt = __ballot(blt), meq = __ballot(beq);
      if (blt)
        keybuf[w][cl + (unsigned)__popcll(mlt & lmask)] =
            ((unsigned)d << 13) | (unsigned)p;
      if (beq) {
        unsigned pos = ce + (unsigned)__popcll(meq & lmask);
        if (pos < r_need)
          keybuf[w][n_lt + pos] = ((unsigned)d << 13) | (unsigned)p;
      }
      cl += (unsigned)__popcll(mlt);
      ce += (unsigned)__popcll(meq);
    }
  }
  __syncthreads();

  // ---- rank-sort the 16 keys (distinct: idx embedded) and emit ----
  if (lane < K_) {
    unsigned my = keybuf[w][lane];
    int rank = 0;
#pragma unroll
    for (int jj = 0; jj < K_; ++jj) rank += (keybuf[w][jj] < my) ? 1 : 0;
    int off = qg * K_ + rank;
    outIdx[off]  = (float)(my & 8191u);  // index
    outDist[off] = (float)(my >> 13);    // distance
  }
}

extern "C" void kernel_launch(void* const* d_in, const int* in_sizes, int n_in,
                              void* d_out, int out_size, void* d_ws, size_t ws_size,
                              hipStream_t stream) {
  const float* qp   = (const float*)d_in[0];
  const float* pp   = (const float*)d_in[1];
  const float* proj = (const float*)d_in[2];
  // d_in[3] is k (always 16) — hardcoded.

  uint64_t* pcodes = (uint64_t*)d_ws;            // B*NP u64
  uint64_t* qcodes = pcodes + (size_t)B_ * NP_;  // B*NQ u64

  float* outIdx  = (float*)d_out;                   // B*NQ*K indices (as float)
  float* outDist = outIdx + (size_t)B_ * NQ_ * K_;  // B*NQ*K distances

  int total_vecs = B_ * (NQ_ + NP_);  // 40960
  hash_kernel<<<total_vecs / 64, 512, 0, stream>>>(qp, pp, proj, qcodes, pcodes);
  select_kernel<<<B_ * NQ_ / 16, 1024, 0, stream>>>(qcodes, pcodes, outIdx, outDist);
}